// Round 2
// baseline (1080.662 us; speedup 1.0000x reference)
//
#include <hip/hip_runtime.h>
#include <stdint.h>

typedef __attribute__((ext_vector_type(8))) short bf16x8;
typedef __attribute__((ext_vector_type(4))) float f32x4;

__device__ __forceinline__ float bf2f(ushort h) {
    union { uint u; float f; } v; v.u = ((uint)h) << 16; return v.f;
}
__device__ __forceinline__ ushort f2bf(float f) {
    union { float f; uint u; } v; v.f = f;
    uint u = v.u;
    return (ushort)((u + 0x7fffu + ((u >> 16) & 1u)) >> 16);
}

// ---------------- graph prep ----------------

__global__ void k_deg(const int* __restrict__ dst, int E, int* __restrict__ deg) {
    int e = blockIdx.x * blockDim.x + threadIdx.x;
    if (e < E) atomicAdd(&deg[dst[e]], 1);
}

__global__ void k_dinv(const int* __restrict__ deg, float* __restrict__ dinv, int NN) {
    int i = blockIdx.x * blockDim.x + threadIdx.x;
    if (i < NN) dinv[i] = 1.0f / sqrtf((float)(deg[i] + 1));  // +1 self loop
}

__global__ void k_scan(const int* __restrict__ deg, int* __restrict__ offs, int NN) {
    __shared__ int lds[1024];
    int t = threadIdx.x;
    int chunk = (NN + 1023) / 1024;
    int b0 = t * chunk;
    int b1 = min(b0 + chunk, NN);
    int s = 0;
    for (int i = b0; i < b1; ++i) s += deg[i];
    lds[t] = s;
    __syncthreads();
    for (int d = 1; d < 1024; d <<= 1) {
        int v = (t >= d) ? lds[t - d] : 0;
        __syncthreads();
        lds[t] += v;
        __syncthreads();
    }
    int excl = (t == 0) ? 0 : lds[t - 1];
    for (int i = b0; i < b1; ++i) { offs[i] = excl; excl += deg[i]; }
}

__global__ void k_fill(const int* __restrict__ src, const int* __restrict__ dst, int E,
                       const float* __restrict__ dinv, const int* __restrict__ offs,
                       int* __restrict__ cur, int* __restrict__ esrc, float* __restrict__ ew) {
    int e = blockIdx.x * blockDim.x + threadIdx.x;
    if (e >= E) return;
    int s = src[e], d = dst[e];
    int p = offs[d] + atomicAdd(&cur[d], 1);
    esrc[p] = s;
    ew[p] = dinv[s] * dinv[d];
}

__global__ void k_group(const uint* __restrict__ x, const uint* __restrict__ nf, int NN,
                        int* __restrict__ gid, int* __restrict__ gcnt) {
    __shared__ int cnt[4];
    if (threadIdx.x < 4) cnt[threadIdx.x] = 0;
    __syncthreads();
    int i = blockIdx.x * blockDim.x + threadIdx.x;
    if (i < NN) {
        const uint* xr = x + (size_t)i * 100;
        bool e0 = true, e1 = true, e2 = true;
        for (int d = 0; d < 100; ++d) {
            uint v = xr[d];
            e0 &= (v == nf[d]);
            e1 &= (v == nf[100 + d]);
            e2 &= (v == nf[200 + d]);
        }
        int g = e0 ? 0 : (e1 ? 3 : (e2 ? 1 : 2));
        gid[i] = g;
        atomicAdd(&cnt[g], 1);
    }
    __syncthreads();
    if (threadIdx.x < 4 && cnt[threadIdx.x]) atomicAdd(&gcnt[threadIdx.x], cnt[threadIdx.x]);
}

// ---------------- aggregation (gather, wave per node), all f32 ----------------

template <int D, int DPAD, bool BR>
__global__ void k_agg(const float* __restrict__ H, float* __restrict__ out,
                      const float* __restrict__ dinv, const int* __restrict__ offs,
                      const int* __restrict__ deg, const int* __restrict__ esrc,
                      const float* __restrict__ ew, const float* __restrict__ bias, int NN) {
    int wid = (int)((blockIdx.x * blockDim.x + threadIdx.x) >> 6);
    int lane = threadIdx.x & 63;
    if (wid >= NN) return;
    constexpr int C = (DPAD + 63) / 64;
    float acc[C];
    float di = dinv[wid];
    float sw = di * di;
#pragma unroll
    for (int c = 0; c < C; ++c) {
        int k = lane + 64 * c;
        acc[c] = (k < D) ? sw * H[(size_t)wid * D + k] : 0.0f;
    }
    int beg = offs[wid];
    int end = beg + deg[wid];
    for (int e = beg; e < end; ++e) {
        int s = esrc[e];
        float w = ew[e];
        const float* hr = H + (size_t)s * D;
#pragma unroll
        for (int c = 0; c < C; ++c) {
            int k = lane + 64 * c;
            if (k < D) acc[c] += w * hr[k];
        }
    }
#pragma unroll
    for (int c = 0; c < C; ++c) {
        int k = lane + 64 * c;
        if (k < DPAD) {
            float v = (k < D) ? acc[c] : 0.0f;
            if (BR) v = fmaxf(v + bias[k], 0.0f);
            out[(size_t)wid * DPAD + k] = v;
        }
    }
}

// ---------------- split helpers ----------------

__device__ __forceinline__ void load8split(const float* p, bf16x8& h, bf16x8& l) {
    float4 u = *(const float4*)p;
    float4 v = *(const float4*)(p + 4);
    float a[8] = {u.x, u.y, u.z, u.w, v.x, v.y, v.z, v.w};
#pragma unroll
    for (int j = 0; j < 8; ++j) {
        ushort hh = f2bf(a[j]);
        ushort ll = f2bf(a[j] - bf2f(hh));
        h[j] = (short)hh;
        l[j] = (short)ll;
    }
}

// ---------------- MFMA GEMM (split bf16x3): C[M,N] = A[M,K] @ BT[N,K]^T (+bias, relu) ----------------
// A is f32; BT pre-split into hi/lo bf16, NP=ceil64(N) zero-padded rows, K mult of 32.

template <bool BR>
__global__ void k_gemm(const float* __restrict__ A,
                       const ushort* __restrict__ BTh, const ushort* __restrict__ BTl,
                       const float* __restrict__ bias, float* __restrict__ Cout,
                       int M, int Nc, int K, int tM, int tN) {
    int w = (int)((blockIdx.x * blockDim.x + threadIdx.x) >> 6);
    if (w >= tM * tN) return;
    int lane = threadIdx.x & 63;
    int tm = w / tN, tn = w % tN;
    int m0 = tm * 32, n0 = tn * 64;
    int l15 = lane & 15, quad = lane >> 4;
    int ko = quad * 8;
    bool r0ok = (m0 + l15) < M;
    bool r1ok = (m0 + 16 + l15) < M;
    const float* a0p = A + (size_t)(m0 + l15) * K + ko;
    const float* a1p = a0p + (size_t)16 * K;
    const ushort* bhp = BTh + (size_t)(n0 + l15) * K + ko;
    const ushort* blp = BTl + (size_t)(n0 + l15) * K + ko;
    f32x4 acc[2][4] = {};
    for (int k = 0; k < K; k += 32) {
        bf16x8 a0h = {}, a0l = {}, a1h = {}, a1l = {};
        if (r0ok) load8split(a0p + k, a0h, a0l);
        if (r1ok) load8split(a1p + k, a1h, a1l);
        bf16x8 bh[4], bl[4];
#pragma unroll
        for (int ni = 0; ni < 4; ++ni) {
            bh[ni] = *(const bf16x8*)(bhp + (size_t)16 * ni * K + k);
            bl[ni] = *(const bf16x8*)(blp + (size_t)16 * ni * K + k);
        }
#pragma unroll
        for (int ni = 0; ni < 4; ++ni) {
            acc[0][ni] = __builtin_amdgcn_mfma_f32_16x16x32_bf16(a0h, bh[ni], acc[0][ni], 0, 0, 0);
            acc[0][ni] = __builtin_amdgcn_mfma_f32_16x16x32_bf16(a0h, bl[ni], acc[0][ni], 0, 0, 0);
            acc[0][ni] = __builtin_amdgcn_mfma_f32_16x16x32_bf16(a0l, bh[ni], acc[0][ni], 0, 0, 0);
            acc[1][ni] = __builtin_amdgcn_mfma_f32_16x16x32_bf16(a1h, bh[ni], acc[1][ni], 0, 0, 0);
            acc[1][ni] = __builtin_amdgcn_mfma_f32_16x16x32_bf16(a1h, bl[ni], acc[1][ni], 0, 0, 0);
            acc[1][ni] = __builtin_amdgcn_mfma_f32_16x16x32_bf16(a1l, bh[ni], acc[1][ni], 0, 0, 0);
        }
    }
    float bia[4] = {0.f, 0.f, 0.f, 0.f};
    if (BR) {
#pragma unroll
        for (int ni = 0; ni < 4; ++ni) {
            int col = n0 + 16 * ni + l15;
            if (col < Nc) bia[ni] = bias[col];
        }
    }
#pragma unroll
    for (int mi = 0; mi < 2; ++mi) {
#pragma unroll
        for (int r = 0; r < 4; ++r) {
            int row = m0 + mi * 16 + quad * 4 + r;
            if (row >= M) continue;
#pragma unroll
            for (int ni = 0; ni < 4; ++ni) {
                int col = n0 + 16 * ni + l15;
                if (col >= Nc) continue;
                float v = acc[mi][ni][r];
                if (BR) v = fmaxf(v + bia[ni], 0.0f);
                Cout[(size_t)row * Nc + col] = v;
            }
        }
    }
}

// ---------------- weight transpose + split: WT[NP][KP] hi/lo bf16, zeros outside ----------------

__global__ void k_tr2(const float* __restrict__ W, ushort* __restrict__ WTh, ushort* __restrict__ WTl,
                      int K, int Nc, int KP, int NP) {
    int idx = blockIdx.x * blockDim.x + threadIdx.x;
    if (idx >= NP * KP) return;
    int n = idx / KP, k = idx % KP;
    float w = (n < Nc && k < K) ? W[(size_t)k * Nc + n] : 0.0f;
    ushort hi = f2bf(w);
    ushort lo = f2bf(w - bf2f(hi));
    WTh[idx] = hi;
    WTl[idx] = lo;
}

// ---------------- group reduce / final ----------------

__global__ void k_reduce(const float* __restrict__ H4, const int* __restrict__ gid,
                         float* __restrict__ gsum, int NN) {
    int d = threadIdx.x;
    if (d >= 200) return;
    int n0 = blockIdx.x * 256;
    int n1 = min(n0 + 256, NN);
    float r0 = 0.f, r1 = 0.f, r2 = 0.f, r3 = 0.f;
    for (int n = n0; n < n1; ++n) {
        int g = gid[n];
        float v = H4[(size_t)n * 200 + d];
        r0 += (g == 0) ? v : 0.f;
        r1 += (g == 1) ? v : 0.f;
        r2 += (g == 2) ? v : 0.f;
        r3 += (g == 3) ? v : 0.f;
    }
    atomicAdd(&gsum[0 * 200 + d], r0);
    atomicAdd(&gsum[1 * 200 + d], r1);
    atomicAdd(&gsum[2 * 200 + d], r2);
    atomicAdd(&gsum[3 * 200 + d], r3);
}

__global__ void k_final(const float* __restrict__ gsum, const int* __restrict__ gcnt,
                        float* __restrict__ out) {
    int j = blockIdx.x * blockDim.x + threadIdx.x;
    if (j >= 800) return;
    int g = j / 200;
    int c = gcnt[g];
    out[j] = (c > 0) ? gsum[j] / (float)c : 0.0f;
}

// ---------------- launch ----------------

extern "C" void kernel_launch(void* const* d_in, const int* in_sizes, int n_in,
                              void* d_out, int out_size, void* d_ws, size_t ws_size,
                              hipStream_t stream) {
    const float* x  = (const float*)d_in[0];
    const float* nf = (const float*)d_in[1];
    const int* ei   = (const int*)d_in[2];
    const float* W1 = (const float*)d_in[3];
    const float* b1 = (const float*)d_in[4];
    const float* W2 = (const float*)d_in[5];
    const float* b2 = (const float*)d_in[6];
    const float* W3 = (const float*)d_in[7];
    const float* b3 = (const float*)d_in[8];
    const float* W4 = (const float*)d_in[9];
    const float* b4 = (const float*)d_in[10];
    float* out = (float*)d_out;

    const int NN = in_sizes[0] / 100;  // 50000 nodes
    const int E  = in_sizes[2] / 2;    // 800000 edges
    const int* src = ei;
    const int* dst = ei + E;

    char* p = (char*)d_ws;
    auto alloc = [&](size_t bytes) -> char* {
        char* r = p;
        p += (bytes + 255) & ~(size_t)255;
        return r;
    };
    char* zz = p;
    int*   deg  = (int*)alloc((size_t)NN * 4);
    int*   cur  = (int*)alloc((size_t)NN * 4);
    int*   gcnt = (int*)alloc(256);
    float* gsum = (float*)alloc(800 * 4);
    size_t zz_bytes = (size_t)(p - zz);
    float* dinv = (float*)alloc((size_t)NN * 4);
    int*   offs = (int*)alloc((size_t)NN * 4);
    int*   gid  = (int*)alloc((size_t)NN * 4);
    int*   esrc = (int*)alloc((size_t)E * 4);
    float* ew   = (float*)alloc((size_t)E * 4);
    ushort* WT1h = (ushort*)alloc((size_t)512 * 128 * 2);
    ushort* WT1l = (ushort*)alloc((size_t)512 * 128 * 2);
    ushort* WT2h = (ushort*)alloc((size_t)256 * 512 * 2);
    ushort* WT2l = (ushort*)alloc((size_t)256 * 512 * 2);
    ushort* WT3h = (ushort*)alloc((size_t)128 * 256 * 2);
    ushort* WT3l = (ushort*)alloc((size_t)128 * 256 * 2);
    ushort* WT4h = (ushort*)alloc((size_t)256 * 128 * 2);
    ushort* WT4l = (ushort*)alloc((size_t)256 * 128 * 2);
    float* bufA = (float*)alloc((size_t)NN * 128 * 4);   // P1 / T3 / P4
    float* bufB = (float*)alloc((size_t)NN * 512 * 4);   // H1 / H2
    float* bufC = (float*)alloc((size_t)NN * 256 * 4);   // T2 / H3 / H4

    hipMemsetAsync(zz, 0, zz_bytes, stream);

    k_deg<<<(E + 255) / 256, 256, 0, stream>>>(dst, E, deg);
    k_dinv<<<(NN + 255) / 256, 256, 0, stream>>>(deg, dinv, NN);
    k_scan<<<1, 1024, 0, stream>>>(deg, offs, NN);
    k_fill<<<(E + 255) / 256, 256, 0, stream>>>(src, dst, E, dinv, offs, cur, esrc, ew);
    k_group<<<(NN + 255) / 256, 256, 0, stream>>>((const uint*)x, (const uint*)nf, NN, gid, gcnt);

    k_tr2<<<(512 * 128 + 255) / 256, 256, 0, stream>>>(W1, WT1h, WT1l, 100, 512, 128, 512);
    k_tr2<<<(256 * 512 + 255) / 256, 256, 0, stream>>>(W2, WT2h, WT2l, 512, 256, 512, 256);
    k_tr2<<<(128 * 256 + 255) / 256, 256, 0, stream>>>(W3, WT3h, WT3l, 256, 128, 256, 128);
    k_tr2<<<(256 * 128 + 255) / 256, 256, 0, stream>>>(W4, WT4h, WT4l, 128, 200, 128, 256);

    int aggBlocks = (NN * 64 + 255) / 256;  // one wave per node

    // P1 = agg(x) -> bufA [NN,128] (K-padded with zeros)
    k_agg<100, 128, false><<<aggBlocks, 256, 0, stream>>>(x, bufA, dinv, offs, deg, esrc, ew, nullptr, NN);
    // H1 = relu(P1 @ W1 + b1) -> bufB [NN,512]
    {
        int tM = (NN + 31) / 32, tN = 512 / 64;
        k_gemm<true><<<(tM * tN + 3) / 4, 256, 0, stream>>>(bufA, WT1h, WT1l, b1, bufB, NN, 512, 128, tM, tN);
    }
    // T2 = H1 @ W2 -> bufC [NN,256]
    {
        int tM = (NN + 31) / 32, tN = 256 / 64;
        k_gemm<false><<<(tM * tN + 3) / 4, 256, 0, stream>>>(bufB, WT2h, WT2l, nullptr, bufC, NN, 256, 512, tM, tN);
    }
    // H2 = relu(agg(T2) + b2) -> bufB [NN,256]
    k_agg<256, 256, true><<<aggBlocks, 256, 0, stream>>>(bufC, bufB, dinv, offs, deg, esrc, ew, b2, NN);
    // T3 = H2 @ W3 -> bufA [NN,128]
    {
        int tM = (NN + 31) / 32, tN = 128 / 64;
        k_gemm<false><<<(tM * tN + 3) / 4, 256, 0, stream>>>(bufB, WT3h, WT3l, nullptr, bufA, NN, 128, 256, tM, tN);
    }
    // H3 = relu(agg(T3) + b3) -> bufC [NN,128]
    k_agg<128, 128, true><<<aggBlocks, 256, 0, stream>>>(bufA, bufC, dinv, offs, deg, esrc, ew, b3, NN);
    // P4 = agg(H3) -> bufA [NN,128]
    k_agg<128, 128, false><<<aggBlocks, 256, 0, stream>>>(bufC, bufA, dinv, offs, deg, esrc, ew, nullptr, NN);
    // H4 = relu(P4 @ W4 + b4) -> bufC [NN,200]
    {
        int tM = (NN + 31) / 32, tN = (200 + 63) / 64;
        k_gemm<true><<<(tM * tN + 3) / 4, 256, 0, stream>>>(bufA, WT4h, WT4l, b4, bufC, NN, 200, 128, tM, tN);
    }
    k_reduce<<<(NN + 255) / 256, 256, 0, stream>>>(bufC, gid, gsum, NN);
    k_final<<<4, 256, 0, stream>>>(gsum, gcnt, out);
}

// Round 3
// 988.082 us; speedup vs baseline: 1.0937x; 1.0937x over previous
//
#include <hip/hip_runtime.h>
#include <stdint.h>

typedef __attribute__((ext_vector_type(8))) short bf16x8;
typedef __attribute__((ext_vector_type(4))) float f32x4;

__device__ __forceinline__ float bf2f(ushort h) {
    union { uint u; float f; } v; v.u = ((uint)h) << 16; return v.f;
}
__device__ __forceinline__ ushort f2bf(float f) {
    union { float f; uint u; } v; v.f = f;
    uint u = v.u;
    return (ushort)((u + 0x7fffu + ((u >> 16) & 1u)) >> 16);
}

// ---------------- graph prep ----------------

__global__ void k_deg(const int* __restrict__ dst, int E, int* __restrict__ deg) {
    int e = blockIdx.x * blockDim.x + threadIdx.x;
    if (e < E) atomicAdd(&deg[dst[e]], 1);
}

__global__ void k_dinv(const int* __restrict__ deg, float* __restrict__ dinv, int NN) {
    int i = blockIdx.x * blockDim.x + threadIdx.x;
    if (i < NN) dinv[i] = 1.0f / sqrtf((float)(deg[i] + 1));  // +1 self loop
}

__global__ void k_scan(const int* __restrict__ deg, int* __restrict__ offs, int NN) {
    __shared__ int lds[1024];
    int t = threadIdx.x;
    int chunk = (NN + 1023) / 1024;
    int b0 = t * chunk;
    int b1 = min(b0 + chunk, NN);
    int s = 0;
    for (int i = b0; i < b1; ++i) s += deg[i];
    lds[t] = s;
    __syncthreads();
    for (int d = 1; d < 1024; d <<= 1) {
        int v = (t >= d) ? lds[t - d] : 0;
        __syncthreads();
        lds[t] += v;
        __syncthreads();
    }
    int excl = (t == 0) ? 0 : lds[t - 1];
    for (int i = b0; i < b1; ++i) { offs[i] = excl; excl += deg[i]; }
}

__global__ void k_fill(const int* __restrict__ src, const int* __restrict__ dst, int E,
                       const float* __restrict__ dinv, const int* __restrict__ offs,
                       int* __restrict__ cur, int* __restrict__ esrc, float* __restrict__ ew) {
    int e = blockIdx.x * blockDim.x + threadIdx.x;
    if (e >= E) return;
    int s = src[e], d = dst[e];
    int p = offs[d] + atomicAdd(&cur[d], 1);
    esrc[p] = s;
    ew[p] = dinv[s] * dinv[d];
}

__global__ void k_group(const uint4* __restrict__ x4, const uint4* __restrict__ nf4, int NN,
                        int* __restrict__ gid, int* __restrict__ gcnt) {
    __shared__ int cnt[4];
    if (threadIdx.x < 4) cnt[threadIdx.x] = 0;
    __syncthreads();
    int i = blockIdx.x * blockDim.x + threadIdx.x;
    if (i < NN) {
        const uint4* xr = x4 + (size_t)i * 25;  // 100 floats = 25 uint4
        bool e0 = true, e1 = true, e2 = true;
#pragma unroll 5
        for (int d = 0; d < 25; ++d) {
            uint4 v = xr[d];
            uint4 a = nf4[d], b = nf4[25 + d], c = nf4[50 + d];
            e0 &= (v.x == a.x) & (v.y == a.y) & (v.z == a.z) & (v.w == a.w);
            e1 &= (v.x == b.x) & (v.y == b.y) & (v.z == b.z) & (v.w == b.w);
            e2 &= (v.x == c.x) & (v.y == c.y) & (v.z == c.z) & (v.w == c.w);
        }
        int g = e0 ? 0 : (e1 ? 3 : (e2 ? 1 : 2));
        gid[i] = g;
        atomicAdd(&cnt[g], 1);
    }
    __syncthreads();
    if (threadIdx.x < 4 && cnt[threadIdx.x]) atomicAdd(&gcnt[threadIdx.x], cnt[threadIdx.x]);
}

// ---------------- aggregation (gather, wave per node) ----------------
// Lane owns contiguous VEC=DPAD/64 floats. Optionally writes split bf16 hi/lo
// (for tensors feeding a GEMM) or f32.

template <int D, int DPAD, bool BR, bool SPLIT>
__global__ void k_agg(const float* __restrict__ H,
                      float* __restrict__ outf, ushort* __restrict__ outh, ushort* __restrict__ outl,
                      const float* __restrict__ dinv, const int* __restrict__ offs,
                      const int* __restrict__ deg, const int* __restrict__ esrc,
                      const float* __restrict__ ew, const float* __restrict__ bias,
                      int NN, int NNpad) {
    int wid = (int)((blockIdx.x * blockDim.x + threadIdx.x) >> 6);
    int lane = threadIdx.x & 63;
    if (wid >= NNpad) return;
    constexpr int VEC = DPAD / 64;
    int c0 = lane * VEC;
    if (wid >= NN) {  // zero pad rows so GEMM A-tiles are clean
#pragma unroll
        for (int j = 0; j < VEC; ++j) {
            if (SPLIT) { outh[(size_t)wid * DPAD + c0 + j] = 0; outl[(size_t)wid * DPAD + c0 + j] = 0; }
            else outf[(size_t)wid * DPAD + c0 + j] = 0.0f;
        }
        return;
    }
    bool act = (c0 + VEC <= D);
    float acc[VEC];
#pragma unroll
    for (int j = 0; j < VEC; ++j) acc[j] = 0.0f;
    float di = dinv[wid];
    float sw = di * di;
    if (act) {
        const float* hp = H + (size_t)wid * D + c0;
#pragma unroll
        for (int j = 0; j < VEC; ++j) acc[j] = sw * hp[j];
    }
    int e = offs[wid];
    int end = e + deg[wid];
    for (; e + 1 < end; e += 2) {
        int s0 = esrc[e], s1 = esrc[e + 1];
        float w0 = ew[e], w1 = ew[e + 1];
        if (act) {
            const float* h0 = H + (size_t)s0 * D + c0;
            const float* h1 = H + (size_t)s1 * D + c0;
#pragma unroll
            for (int j = 0; j < VEC; ++j) acc[j] += w0 * h0[j];
#pragma unroll
            for (int j = 0; j < VEC; ++j) acc[j] += w1 * h1[j];
        }
    }
    if (e < end) {
        int s0 = esrc[e];
        float w0 = ew[e];
        if (act) {
            const float* h0 = H + (size_t)s0 * D + c0;
#pragma unroll
            for (int j = 0; j < VEC; ++j) acc[j] += w0 * h0[j];
        }
    }
#pragma unroll
    for (int j = 0; j < VEC; ++j) {
        float v = act ? acc[j] : 0.0f;
        if (BR && act) v = fmaxf(v + bias[c0 + j], 0.0f);
        if (SPLIT) {
            ushort hi = f2bf(v);
            ushort lo = f2bf(v - bf2f(hi));
            outh[(size_t)wid * DPAD + c0 + j] = hi;
            outl[(size_t)wid * DPAD + c0 + j] = lo;
        } else {
            outf[(size_t)wid * DPAD + c0 + j] = v;
        }
    }
}

// ---------------- MFMA GEMM (pre-split bf16 hi/lo, 3-term): ----------------
// C[M,N] = A[M,K] @ BT[N,K]^T (+bias, relu). Wave tile 64x64.
// OUT: 0 = f32 to Cf (ld Nc), 1 = split hi/lo to Ch/Cl.

template <bool BR, int OUT>
__global__ void k_gemm(const ushort* __restrict__ Ah, const ushort* __restrict__ Al,
                       const ushort* __restrict__ Bh, const ushort* __restrict__ Bl,
                       const float* __restrict__ bias,
                       float* __restrict__ Cf, ushort* __restrict__ Ch, ushort* __restrict__ Cl,
                       int M, int Nc, int K, int tM, int tN) {
    int w = (int)((blockIdx.x * blockDim.x + threadIdx.x) >> 6);
    if (w >= tM * tN) return;
    int lane = threadIdx.x & 63;
    int tm = w / tN, tn = w % tN;
    int m0 = tm * 64, n0 = tn * 64;
    int l15 = lane & 15, quad = lane >> 4;
    int ko = quad * 8;
    const ushort* ah = Ah + (size_t)(m0 + l15) * K + ko;
    const ushort* al = Al + (size_t)(m0 + l15) * K + ko;
    const ushort* bh = Bh + (size_t)(n0 + l15) * K + ko;
    const ushort* bl = Bl + (size_t)(n0 + l15) * K + ko;
    f32x4 acc[4][4] = {};
    for (int k = 0; k < K; k += 32) {
        bf16x8 Afh[4], Afl[4], Bfh[4], Bfl[4];
#pragma unroll
        for (int i = 0; i < 4; ++i) {
            size_t ro = (size_t)16 * i * K + k;
            Afh[i] = *(const bf16x8*)(ah + ro);
            Afl[i] = *(const bf16x8*)(al + ro);
            Bfh[i] = *(const bf16x8*)(bh + ro);
            Bfl[i] = *(const bf16x8*)(bl + ro);
        }
#pragma unroll
        for (int mi = 0; mi < 4; ++mi)
#pragma unroll
            for (int ni = 0; ni < 4; ++ni) {
                acc[mi][ni] = __builtin_amdgcn_mfma_f32_16x16x32_bf16(Afh[mi], Bfh[ni], acc[mi][ni], 0, 0, 0);
                acc[mi][ni] = __builtin_amdgcn_mfma_f32_16x16x32_bf16(Afh[mi], Bfl[ni], acc[mi][ni], 0, 0, 0);
                acc[mi][ni] = __builtin_amdgcn_mfma_f32_16x16x32_bf16(Afl[mi], Bfh[ni], acc[mi][ni], 0, 0, 0);
            }
    }
    float bia[4] = {0.f, 0.f, 0.f, 0.f};
    if (BR) {
#pragma unroll
        for (int ni = 0; ni < 4; ++ni) {
            int col = n0 + 16 * ni + l15;
            if (col < Nc) bia[ni] = bias[col];
        }
    }
#pragma unroll
    for (int mi = 0; mi < 4; ++mi) {
#pragma unroll
        for (int r = 0; r < 4; ++r) {
            int row = m0 + mi * 16 + quad * 4 + r;
            if (row >= M) continue;
#pragma unroll
            for (int ni = 0; ni < 4; ++ni) {
                int col = n0 + 16 * ni + l15;
                if (col >= Nc) continue;
                float v = acc[mi][ni][r];
                if (BR) v = fmaxf(v + bia[ni], 0.0f);
                if (OUT == 0) {
                    Cf[(size_t)row * Nc + col] = v;
                } else {
                    ushort hi = f2bf(v);
                    ushort lo = f2bf(v - bf2f(hi));
                    Ch[(size_t)row * Nc + col] = hi;
                    Cl[(size_t)row * Nc + col] = lo;
                }
            }
        }
    }
}

// ---------------- weight transpose + split: WT[NP][KP] hi/lo bf16, zeros outside ----------------

__global__ void k_tr2(const float* __restrict__ W, ushort* __restrict__ WTh, ushort* __restrict__ WTl,
                      int K, int Nc, int KP, int NP) {
    int idx = blockIdx.x * blockDim.x + threadIdx.x;
    if (idx >= NP * KP) return;
    int n = idx / KP, k = idx % KP;
    float w = (n < Nc && k < K) ? W[(size_t)k * Nc + n] : 0.0f;
    ushort hi = f2bf(w);
    ushort lo = f2bf(w - bf2f(hi));
    WTh[idx] = hi;
    WTl[idx] = lo;
}

// ---------------- group reduce / final ----------------

__global__ void k_reduce(const float* __restrict__ H4, const int* __restrict__ gid,
                         float* __restrict__ gsum, int NN) {
    int d = threadIdx.x;
    if (d >= 200) return;
    int n0 = blockIdx.x * 256;
    int n1 = min(n0 + 256, NN);
    float r0 = 0.f, r1 = 0.f, r2 = 0.f, r3 = 0.f;
    for (int n = n0; n < n1; ++n) {
        int g = gid[n];
        float v = H4[(size_t)n * 200 + d];
        r0 += (g == 0) ? v : 0.f;
        r1 += (g == 1) ? v : 0.f;
        r2 += (g == 2) ? v : 0.f;
        r3 += (g == 3) ? v : 0.f;
    }
    atomicAdd(&gsum[0 * 200 + d], r0);
    atomicAdd(&gsum[1 * 200 + d], r1);
    atomicAdd(&gsum[2 * 200 + d], r2);
    atomicAdd(&gsum[3 * 200 + d], r3);
}

__global__ void k_final(const float* __restrict__ gsum, const int* __restrict__ gcnt,
                        float* __restrict__ out) {
    int j = blockIdx.x * blockDim.x + threadIdx.x;
    if (j >= 800) return;
    int g = j / 200;
    int c = gcnt[g];
    out[j] = (c > 0) ? gsum[j] / (float)c : 0.0f;
}

// ---------------- launch ----------------

extern "C" void kernel_launch(void* const* d_in, const int* in_sizes, int n_in,
                              void* d_out, int out_size, void* d_ws, size_t ws_size,
                              hipStream_t stream) {
    const float* x  = (const float*)d_in[0];
    const float* nf = (const float*)d_in[1];
    const int* ei   = (const int*)d_in[2];
    const float* W1 = (const float*)d_in[3];
    const float* b1 = (const float*)d_in[4];
    const float* W2 = (const float*)d_in[5];
    const float* b2 = (const float*)d_in[6];
    const float* W3 = (const float*)d_in[7];
    const float* b3 = (const float*)d_in[8];
    const float* W4 = (const float*)d_in[9];
    const float* b4 = (const float*)d_in[10];
    float* out = (float*)d_out;

    const int NN = in_sizes[0] / 100;  // 50000
    const int E  = in_sizes[2] / 2;    // 800000
    const int M64 = ((NN + 63) / 64) * 64;
    const int* src = ei;
    const int* dst = ei + E;

    char* p = (char*)d_ws;
    auto alloc = [&](size_t bytes) -> char* {
        char* r = p;
        p += (bytes + 255) & ~(size_t)255;
        return r;
    };
    char* zz = p;
    int*   deg  = (int*)alloc((size_t)NN * 4);
    int*   cur  = (int*)alloc((size_t)NN * 4);
    int*   gcnt = (int*)alloc(256);
    float* gsum = (float*)alloc(800 * 4);
    size_t zz_bytes = (size_t)(p - zz);
    float* dinv = (float*)alloc((size_t)NN * 4);
    int*   offs = (int*)alloc((size_t)NN * 4);
    int*   gid  = (int*)alloc((size_t)NN * 4);
    int*   esrc = (int*)alloc((size_t)E * 4);
    float* ew   = (float*)alloc((size_t)E * 4);
    ushort* WT1h = (ushort*)alloc((size_t)512 * 128 * 2);
    ushort* WT1l = (ushort*)alloc((size_t)512 * 128 * 2);
    ushort* WT2h = (ushort*)alloc((size_t)256 * 512 * 2);
    ushort* WT2l = (ushort*)alloc((size_t)256 * 512 * 2);
    ushort* WT3h = (ushort*)alloc((size_t)128 * 256 * 2);
    ushort* WT3l = (ushort*)alloc((size_t)128 * 256 * 2);
    ushort* WT4h = (ushort*)alloc((size_t)256 * 128 * 2);
    ushort* WT4l = (ushort*)alloc((size_t)256 * 128 * 2);
    // Region A (102.4MB): H1 split; later P4 split
    ushort* H1h = (ushort*)alloc((size_t)M64 * 512 * 2);
    ushort* H1l = (ushort*)alloc((size_t)M64 * 512 * 2);
    ushort* P4h = H1h;
    ushort* P4l = H1h + (size_t)M64 * 128;
    // Region B (51.3MB): T2 f32; later H3 f32
    float* T2 = (float*)alloc((size_t)M64 * 256 * 4);
    float* H3 = T2;
    // Region C (51.3MB): P1 split; later H2 split; later H4 f32
    char* regC = alloc((size_t)M64 * 256 * 2 * 2);
    ushort* P1h = (ushort*)regC;
    ushort* P1l = (ushort*)(regC + (size_t)M64 * 128 * 2);
    ushort* H2h = (ushort*)regC;
    ushort* H2l = (ushort*)(regC + (size_t)M64 * 256 * 2);
    float*  H4  = (float*)regC;
    // Region D (25.7MB): T3 f32
    float* T3 = (float*)alloc((size_t)M64 * 128 * 4);

    hipMemsetAsync(zz, 0, zz_bytes, stream);

    k_deg<<<(E + 255) / 256, 256, 0, stream>>>(dst, E, deg);
    k_dinv<<<(NN + 255) / 256, 256, 0, stream>>>(deg, dinv, NN);
    k_scan<<<1, 1024, 0, stream>>>(deg, offs, NN);
    k_fill<<<(E + 255) / 256, 256, 0, stream>>>(src, dst, E, dinv, offs, cur, esrc, ew);
    k_group<<<(NN + 255) / 256, 256, 0, stream>>>((const uint4*)x, (const uint4*)nf, NN, gid, gcnt);

    k_tr2<<<(512 * 128 + 255) / 256, 256, 0, stream>>>(W1, WT1h, WT1l, 100, 512, 128, 512);
    k_tr2<<<(256 * 512 + 255) / 256, 256, 0, stream>>>(W2, WT2h, WT2l, 512, 256, 512, 256);
    k_tr2<<<(128 * 256 + 255) / 256, 256, 0, stream>>>(W3, WT3h, WT3l, 256, 128, 256, 128);
    k_tr2<<<(256 * 128 + 255) / 256, 256, 0, stream>>>(W4, WT4h, WT4l, 128, 200, 128, 256);

    int aggBlocks = M64 / 4;  // one wave per node incl. pad rows

    // P1 = agg(x) -> split [M64,128]
    k_agg<100, 128, false, true><<<aggBlocks, 256, 0, stream>>>(x, nullptr, P1h, P1l, dinv, offs, deg, esrc, ew, nullptr, NN, M64);
    // H1 = relu(P1 @ W1 + b1) -> split [M64,512]
    {
        int tM = M64 / 64, tN = 512 / 64;
        k_gemm<true, 1><<<(tM * tN + 3) / 4, 256, 0, stream>>>(P1h, P1l, WT1h, WT1l, b1, nullptr, H1h, H1l, NN, 512, 128, tM, tN);
    }
    // T2 = H1 @ W2 -> f32 [NN,256]
    {
        int tM = M64 / 64, tN = 256 / 64;
        k_gemm<false, 0><<<(tM * tN + 3) / 4, 256, 0, stream>>>(H1h, H1l, WT2h, WT2l, nullptr, T2, nullptr, nullptr, NN, 256, 512, tM, tN);
    }
    // H2 = relu(agg(T2) + b2) -> split [M64,256]
    k_agg<256, 256, true, true><<<aggBlocks, 256, 0, stream>>>(T2, nullptr, H2h, H2l, dinv, offs, deg, esrc, ew, b2, NN, M64);
    // T3 = H2 @ W3 -> f32 [NN,128]
    {
        int tM = M64 / 64, tN = 128 / 64;
        k_gemm<false, 0><<<(tM * tN + 3) / 4, 256, 0, stream>>>(H2h, H2l, WT3h, WT3l, nullptr, T3, nullptr, nullptr, NN, 128, 256, tM, tN);
    }
    // H3 = relu(agg(T3) + b3) -> f32 [NN,128]  (into region B; T2 dead)
    k_agg<128, 128, true, false><<<aggBlocks, 256, 0, stream>>>(T3, H3, nullptr, nullptr, dinv, offs, deg, esrc, ew, b3, NN, M64);
    // P4 = agg(H3) -> split [M64,128]  (into region A; H1 dead)
    k_agg<128, 128, false, true><<<aggBlocks, 256, 0, stream>>>(H3, nullptr, P4h, P4l, dinv, offs, deg, esrc, ew, nullptr, NN, M64);
    // H4 = relu(P4 @ W4 + b4) -> f32 [NN,200]  (into region C; H2 dead)
    {
        int tM = M64 / 64, tN = 256 / 64;
        k_gemm<true, 0><<<(tM * tN + 3) / 4, 256, 0, stream>>>(P4h, P4l, WT4h, WT4l, b4, H4, nullptr, nullptr, NN, 200, 128, tM, tN);
    }
    k_reduce<<<(NN + 255) / 256, 256, 0, stream>>>(H4, gid, gsum, NN);
    k_final<<<4, 256, 0, stream>>>(gsum, gcnt, out);
}

// Round 4
// 802.118 us; speedup vs baseline: 1.3473x; 1.2318x over previous
//
#include <hip/hip_runtime.h>
#include <stdint.h>

typedef __attribute__((ext_vector_type(8))) short bf16x8;
typedef __attribute__((ext_vector_type(4))) float f32x4;

__device__ __forceinline__ float bf2f(ushort h) {
    union { uint u; float f; } v; v.u = ((uint)h) << 16; return v.f;
}
__device__ __forceinline__ ushort f2bf(float f) {
    union { float f; uint u; } v; v.f = f;
    uint u = v.u;
    return (ushort)((u + 0x7fffu + ((u >> 16) & 1u)) >> 16);
}

// async global->LDS, 16B per lane; LDS dest = wave-uniform base + lane*16
__device__ __forceinline__ void gll(const ushort* g, ushort* l) {
    __builtin_amdgcn_global_load_lds(
        (const __attribute__((address_space(1))) void*)g,
        (__attribute__((address_space(3))) void*)l, 16, 0, 0);
}

// ---------------- graph prep ----------------

__global__ void k_deg(const int* __restrict__ dst, int E, int* __restrict__ deg) {
    int e = blockIdx.x * blockDim.x + threadIdx.x;
    if (e < E) atomicAdd(&deg[dst[e]], 1);
}

__global__ void k_dinv(const int* __restrict__ deg, float* __restrict__ dinv, int NN) {
    int i = blockIdx.x * blockDim.x + threadIdx.x;
    if (i < NN) dinv[i] = 1.0f / sqrtf((float)(deg[i] + 1));  // +1 self loop
}

__global__ void k_scan(const int* __restrict__ deg, int* __restrict__ offs, int NN) {
    __shared__ int lds[1024];
    int t = threadIdx.x;
    int chunk = (NN + 1023) / 1024;
    int b0 = t * chunk;
    int b1 = min(b0 + chunk, NN);
    int s = 0;
    for (int i = b0; i < b1; ++i) s += deg[i];
    lds[t] = s;
    __syncthreads();
    for (int d = 1; d < 1024; d <<= 1) {
        int v = (t >= d) ? lds[t - d] : 0;
        __syncthreads();
        lds[t] += v;
        __syncthreads();
    }
    int excl = (t == 0) ? 0 : lds[t - 1];
    for (int i = b0; i < b1; ++i) { offs[i] = excl; excl += deg[i]; }
}

__global__ void k_fill(const int* __restrict__ src, const int* __restrict__ dst, int E,
                       const float* __restrict__ dinv, const int* __restrict__ offs,
                       int* __restrict__ cur, int* __restrict__ esrc, float* __restrict__ ew) {
    int e = blockIdx.x * blockDim.x + threadIdx.x;
    if (e >= E) return;
    int s = src[e], d = dst[e];
    int p = offs[d] + atomicAdd(&cur[d], 1);
    esrc[p] = s;
    ew[p] = dinv[s] * dinv[d];
}

__global__ void k_group(const uint4* __restrict__ x4, const uint4* __restrict__ nf4, int NN,
                        int* __restrict__ gid, int* __restrict__ gcnt) {
    __shared__ int cnt[4];
    if (threadIdx.x < 4) cnt[threadIdx.x] = 0;
    __syncthreads();
    int i = blockIdx.x * blockDim.x + threadIdx.x;
    if (i < NN) {
        const uint4* xr = x4 + (size_t)i * 25;  // 100 floats = 25 uint4
        bool e0 = true, e1 = true, e2 = true;
#pragma unroll 5
        for (int d = 0; d < 25; ++d) {
            uint4 v = xr[d];
            uint4 a = nf4[d], b = nf4[25 + d], c = nf4[50 + d];
            e0 &= (v.x == a.x) & (v.y == a.y) & (v.z == a.z) & (v.w == a.w);
            e1 &= (v.x == b.x) & (v.y == b.y) & (v.z == b.z) & (v.w == b.w);
            e2 &= (v.x == c.x) & (v.y == c.y) & (v.z == c.z) & (v.w == c.w);
        }
        int g = e0 ? 0 : (e1 ? 3 : (e2 ? 1 : 2));
        gid[i] = g;
        atomicAdd(&cnt[g], 1);
    }
    __syncthreads();
    if (threadIdx.x < 4 && cnt[threadIdx.x]) atomicAdd(&gcnt[threadIdx.x], cnt[threadIdx.x]);
}

// ---------------- aggregation (gather, wave per node) ----------------

template <int D, int DPAD, bool BR, bool SPLIT>
__global__ void k_agg(const float* __restrict__ H,
                      float* __restrict__ outf, ushort* __restrict__ outh, ushort* __restrict__ outl,
                      const float* __restrict__ dinv, const int* __restrict__ offs,
                      const int* __restrict__ deg, const int* __restrict__ esrc,
                      const float* __restrict__ ew, const float* __restrict__ bias,
                      int NN, int NNpad) {
    int wid = (int)((blockIdx.x * blockDim.x + threadIdx.x) >> 6);
    int lane = threadIdx.x & 63;
    if (wid >= NNpad) return;
    constexpr int VEC = DPAD / 64;
    int c0 = lane * VEC;
    if (wid >= NN) {  // zero pad rows so GEMM A-tiles are clean
#pragma unroll
        for (int j = 0; j < VEC; ++j) {
            if (SPLIT) { outh[(size_t)wid * DPAD + c0 + j] = 0; outl[(size_t)wid * DPAD + c0 + j] = 0; }
            else outf[(size_t)wid * DPAD + c0 + j] = 0.0f;
        }
        return;
    }
    bool act = (c0 + VEC <= D);
    float acc[VEC];
#pragma unroll
    for (int j = 0; j < VEC; ++j) acc[j] = 0.0f;
    float di = dinv[wid];
    float sw = di * di;
    if (act) {
        const float* hp = H + (size_t)wid * D + c0;
#pragma unroll
        for (int j = 0; j < VEC; ++j) acc[j] = sw * hp[j];
    }
    int e = offs[wid];
    int end = e + deg[wid];
    for (; e + 1 < end; e += 2) {
        int s0 = esrc[e], s1 = esrc[e + 1];
        float w0 = ew[e], w1 = ew[e + 1];
        if (act) {
            const float* h0 = H + (size_t)s0 * D + c0;
            const float* h1 = H + (size_t)s1 * D + c0;
#pragma unroll
            for (int j = 0; j < VEC; ++j) acc[j] += w0 * h0[j];
#pragma unroll
            for (int j = 0; j < VEC; ++j) acc[j] += w1 * h1[j];
        }
    }
    if (e < end) {
        int s0 = esrc[e];
        float w0 = ew[e];
        if (act) {
            const float* h0 = H + (size_t)s0 * D + c0;
#pragma unroll
            for (int j = 0; j < VEC; ++j) acc[j] += w0 * h0[j];
        }
    }
#pragma unroll
    for (int j = 0; j < VEC; ++j) {
        float v = act ? acc[j] : 0.0f;
        if (BR && act) v = fmaxf(v + bias[c0 + j], 0.0f);
        if (SPLIT) {
            ushort hi = f2bf(v);
            ushort lo = f2bf(v - bf2f(hi));
            outh[(size_t)wid * DPAD + c0 + j] = hi;
            outl[(size_t)wid * DPAD + c0 + j] = lo;
        } else {
            outf[(size_t)wid * DPAD + c0 + j] = v;
        }
    }
}

// ---------------- MFMA GEMM (pre-split bf16 hi/lo, 3-term), LDS-tiled ----------------
// C[M,N] = A[M,K] @ BT[N,K]^T (+bias, relu). Block tile 128x128, 4 waves (64x64 each).
// Staging: global_load_lds width 16, BK=32 -> 4 x 8KB LDS. LDS-buffered epilogue
// for coalesced stores. OUT: 0 = f32 to Cf, 1 = split hi/lo (packed u32 stores).

template <bool BR, int OUT>
__global__ __launch_bounds__(256) void k_gemm(
        const ushort* __restrict__ Ah, const ushort* __restrict__ Al,
        const ushort* __restrict__ Bh, const ushort* __restrict__ Bl,
        const float* __restrict__ bias,
        float* __restrict__ Cf, ushort* __restrict__ Ch, ushort* __restrict__ Cl,
        int Nc, int K, int tNb) {
    __shared__ union {
        ushort st[4][128 * 32];
        float epi[64 * 132];
    } sm;
    int bm = blockIdx.x / tNb, bn = blockIdx.x % tNb;
    int m0 = bm * 128, n0 = bn * 128;
    int wv = threadIdx.x >> 6, lane = threadIdx.x & 63;
    int l15 = lane & 15, quad = lane >> 4;
    // this wave stages one of the 4 operand streams
    const ushort* gT = (wv == 0) ? Ah + (size_t)m0 * K
                     : (wv == 1) ? Al + (size_t)m0 * K
                     : (wv == 2) ? Bh + (size_t)n0 * K
                     :             Bl + (size_t)n0 * K;
    ushort* sT = sm.st[wv];
    const ushort* gBase = gT + (size_t)(lane >> 2) * K + (lane & 3) * 8;
    int wm = (wv >> 1) * 64, wn = (wv & 1) * 64;
    const ushort* sAh_ = sm.st[0];
    const ushort* sAl_ = sm.st[1];
    const ushort* sBh_ = sm.st[2];
    const ushort* sBl_ = sm.st[3];
    f32x4 acc[4][4] = {};
    for (int k0 = 0; k0 < K; k0 += 32) {
#pragma unroll
        for (int i = 0; i < 8; ++i)
            gll(gBase + (size_t)(16 * i) * K + k0, sT + i * 512);
        __syncthreads();
        bf16x8 Afh[4], Afl[4], Bfh[4], Bfl[4];
#pragma unroll
        for (int i = 0; i < 4; ++i) {
            int ra = (wm + 16 * i + l15) * 32 + quad * 8;
            int rb = (wn + 16 * i + l15) * 32 + quad * 8;
            Afh[i] = *(const bf16x8*)(sAh_ + ra);
            Afl[i] = *(const bf16x8*)(sAl_ + ra);
            Bfh[i] = *(const bf16x8*)(sBh_ + rb);
            Bfl[i] = *(const bf16x8*)(sBl_ + rb);
        }
#pragma unroll
        for (int mi = 0; mi < 4; ++mi)
#pragma unroll
            for (int ni = 0; ni < 4; ++ni) {
                acc[mi][ni] = __builtin_amdgcn_mfma_f32_16x16x32_bf16(Afh[mi], Bfh[ni], acc[mi][ni], 0, 0, 0);
                acc[mi][ni] = __builtin_amdgcn_mfma_f32_16x16x32_bf16(Afh[mi], Bfl[ni], acc[mi][ni], 0, 0, 0);
                acc[mi][ni] = __builtin_amdgcn_mfma_f32_16x16x32_bf16(Afl[mi], Bfh[ni], acc[mi][ni], 0, 0, 0);
            }
        __syncthreads();
    }
    float bia[4] = {0.f, 0.f, 0.f, 0.f};
    if (BR) {
#pragma unroll
        for (int ni = 0; ni < 4; ++ni) {
            int col = n0 + wn + 16 * ni + l15;
            if (col < Nc) bia[ni] = bias[col];
        }
    }
    // epilogue via LDS, two 64-row halves
    float* epi = sm.epi;
    int t = threadIdx.x;
    for (int half = 0; half < 2; ++half) {
        if ((wv >> 1) == half) {
#pragma unroll
            for (int mi = 0; mi < 4; ++mi)
#pragma unroll
                for (int r = 0; r < 4; ++r) {
                    int rl = mi * 16 + quad * 4 + r;
#pragma unroll
                    for (int ni = 0; ni < 4; ++ni) {
                        float v = acc[mi][ni][r];
                        if (BR) v = fmaxf(v + bia[ni], 0.0f);
                        epi[rl * 132 + wn + ni * 16 + l15] = v;
                    }
                }
        }
        __syncthreads();
#pragma unroll
        for (int j = 0; j < 16; ++j) {
            int e = (j * 256 + t) * 2;
            int rl = e >> 7, cl = e & 127;
            int grow = m0 + half * 64 + rl;
            int gcol = n0 + cl;
            float v0 = epi[rl * 132 + cl];
            float v1 = epi[rl * 132 + cl + 1];
            if (OUT == 0) {
                if (gcol < Nc) {
                    float2 w; w.x = v0; w.y = v1;
                    *(float2*)&Cf[(size_t)grow * Nc + gcol] = w;
                }
            } else {
                ushort h0 = f2bf(v0), h1 = f2bf(v1);
                ushort l0 = f2bf(v0 - bf2f(h0)), l1 = f2bf(v1 - bf2f(h1));
                *(uint*)&Ch[(size_t)grow * Nc + gcol] = (uint)h0 | ((uint)h1 << 16);
                *(uint*)&Cl[(size_t)grow * Nc + gcol] = (uint)l0 | ((uint)l1 << 16);
            }
        }
        __syncthreads();
    }
}

// ---------------- weight transpose + split: WT[NP][KP] hi/lo bf16, zeros outside ----------------

__global__ void k_tr2(const float* __restrict__ W, ushort* __restrict__ WTh, ushort* __restrict__ WTl,
                      int K, int Nc, int KP, int NP) {
    int idx = blockIdx.x * blockDim.x + threadIdx.x;
    if (idx >= NP * KP) return;
    int n = idx / KP, k = idx % KP;
    float w = (n < Nc && k < K) ? W[(size_t)k * Nc + n] : 0.0f;
    ushort hi = f2bf(w);
    ushort lo = f2bf(w - bf2f(hi));
    WTh[idx] = hi;
    WTl[idx] = lo;
}

// ---------------- group reduce / final ----------------

__global__ void k_reduce(const float* __restrict__ H4, const int* __restrict__ gid,
                         float* __restrict__ gsum, int NN) {
    int d = threadIdx.x;
    if (d >= 200) return;
    int n0 = blockIdx.x * 256;
    int n1 = min(n0 + 256, NN);
    float r0 = 0.f, r1 = 0.f, r2 = 0.f, r3 = 0.f;
    for (int n = n0; n < n1; ++n) {
        int g = gid[n];
        float v = H4[(size_t)n * 200 + d];
        r0 += (g == 0) ? v : 0.f;
        r1 += (g == 1) ? v : 0.f;
        r2 += (g == 2) ? v : 0.f;
        r3 += (g == 3) ? v : 0.f;
    }
    atomicAdd(&gsum[0 * 200 + d], r0);
    atomicAdd(&gsum[1 * 200 + d], r1);
    atomicAdd(&gsum[2 * 200 + d], r2);
    atomicAdd(&gsum[3 * 200 + d], r3);
}

__global__ void k_final(const float* __restrict__ gsum, const int* __restrict__ gcnt,
                        float* __restrict__ out) {
    int j = blockIdx.x * blockDim.x + threadIdx.x;
    if (j >= 800) return;
    int g = j / 200;
    int c = gcnt[g];
    out[j] = (c > 0) ? gsum[j] / (float)c : 0.0f;
}

// ---------------- launch ----------------

extern "C" void kernel_launch(void* const* d_in, const int* in_sizes, int n_in,
                              void* d_out, int out_size, void* d_ws, size_t ws_size,
                              hipStream_t stream) {
    const float* x  = (const float*)d_in[0];
    const float* nf = (const float*)d_in[1];
    const int* ei   = (const int*)d_in[2];
    const float* W1 = (const float*)d_in[3];
    const float* b1 = (const float*)d_in[4];
    const float* W2 = (const float*)d_in[5];
    const float* b2 = (const float*)d_in[6];
    const float* W3 = (const float*)d_in[7];
    const float* b3 = (const float*)d_in[8];
    const float* W4 = (const float*)d_in[9];
    const float* b4 = (const float*)d_in[10];
    float* out = (float*)d_out;

    const int NN = in_sizes[0] / 100;  // 50000
    const int E  = in_sizes[2] / 2;    // 800000
    const int MPAD = ((NN + 127) / 128) * 128;  // 50048
    const int* src = ei;
    const int* dst = ei + E;

    char* p = (char*)d_ws;
    auto alloc = [&](size_t bytes) -> char* {
        char* r = p;
        p += (bytes + 255) & ~(size_t)255;
        return r;
    };
    char* zz = p;
    int*   deg  = (int*)alloc((size_t)NN * 4);
    int*   cur  = (int*)alloc((size_t)NN * 4);
    int*   gcnt = (int*)alloc(256);
    float* gsum = (float*)alloc(800 * 4);
    size_t zz_bytes = (size_t)(p - zz);
    float* dinv = (float*)alloc((size_t)NN * 4);
    int*   offs = (int*)alloc((size_t)NN * 4);
    int*   gid  = (int*)alloc((size_t)NN * 4);
    int*   esrc = (int*)alloc((size_t)E * 4);
    float* ew   = (float*)alloc((size_t)E * 4);
    ushort* WT1h = (ushort*)alloc((size_t)512 * 128 * 2);
    ushort* WT1l = (ushort*)alloc((size_t)512 * 128 * 2);
    ushort* WT2h = (ushort*)alloc((size_t)256 * 512 * 2);
    ushort* WT2l = (ushort*)alloc((size_t)256 * 512 * 2);
    ushort* WT3h = (ushort*)alloc((size_t)128 * 256 * 2);
    ushort* WT3l = (ushort*)alloc((size_t)128 * 256 * 2);
    ushort* WT4h = (ushort*)alloc((size_t)256 * 128 * 2);
    ushort* WT4l = (ushort*)alloc((size_t)256 * 128 * 2);
    // Region A: H1 split; later P4 split
    ushort* H1h = (ushort*)alloc((size_t)MPAD * 512 * 2);
    ushort* H1l = (ushort*)alloc((size_t)MPAD * 512 * 2);
    ushort* P4h = H1h;
    ushort* P4l = H1h + (size_t)MPAD * 128;
    // Region B: T2 f32; later H3 f32
    float* T2 = (float*)alloc((size_t)MPAD * 256 * 4);
    float* H3 = T2;
    // Region C: P1 split; later H2 split; later H4 f32
    char* regC = alloc((size_t)MPAD * 256 * 2 * 2);
    ushort* P1h = (ushort*)regC;
    ushort* P1l = (ushort*)(regC + (size_t)MPAD * 128 * 2);
    ushort* H2h = (ushort*)regC;
    ushort* H2l = (ushort*)(regC + (size_t)MPAD * 256 * 2);
    float*  H4  = (float*)regC;
    // Region D: T3 f32
    float* T3 = (float*)alloc((size_t)MPAD * 128 * 4);

    hipMemsetAsync(zz, 0, zz_bytes, stream);

    k_deg<<<(E + 255) / 256, 256, 0, stream>>>(dst, E, deg);
    k_dinv<<<(NN + 255) / 256, 256, 0, stream>>>(deg, dinv, NN);
    k_scan<<<1, 1024, 0, stream>>>(deg, offs, NN);
    k_fill<<<(E + 255) / 256, 256, 0, stream>>>(src, dst, E, dinv, offs, cur, esrc, ew);
    k_group<<<(NN + 255) / 256, 256, 0, stream>>>((const uint4*)x, (const uint4*)nf, NN, gid, gcnt);

    k_tr2<<<(512 * 128 + 255) / 256, 256, 0, stream>>>(W1, WT1h, WT1l, 100, 512, 128, 512);
    k_tr2<<<(256 * 512 + 255) / 256, 256, 0, stream>>>(W2, WT2h, WT2l, 512, 256, 512, 256);
    k_tr2<<<(128 * 256 + 255) / 256, 256, 0, stream>>>(W3, WT3h, WT3l, 256, 128, 256, 128);
    k_tr2<<<(256 * 128 + 255) / 256, 256, 0, stream>>>(W4, WT4h, WT4l, 128, 200, 128, 256);

    int aggBlocks = MPAD / 4;  // one wave per node incl. pad rows
    int mB = MPAD / 128;

    // P1 = agg(x) -> split [MPAD,128]
    k_agg<100, 128, false, true><<<aggBlocks, 256, 0, stream>>>(x, nullptr, P1h, P1l, dinv, offs, deg, esrc, ew, nullptr, NN, MPAD);
    // H1 = relu(P1 @ W1 + b1) -> split [MPAD,512]
    k_gemm<true, 1><<<mB * 4, 256, 0, stream>>>(P1h, P1l, WT1h, WT1l, b1, nullptr, H1h, H1l, 512, 128, 4);
    // T2 = H1 @ W2 -> f32 [MPAD,256]
    k_gemm<false, 0><<<mB * 2, 256, 0, stream>>>(H1h, H1l, WT2h, WT2l, nullptr, T2, nullptr, nullptr, 256, 512, 2);
    // H2 = relu(agg(T2) + b2) -> split [MPAD,256]
    k_agg<256, 256, true, true><<<aggBlocks, 256, 0, stream>>>(T2, nullptr, H2h, H2l, dinv, offs, deg, esrc, ew, b2, NN, MPAD);
    // T3 = H2 @ W3 -> f32 [MPAD,128]
    k_gemm<false, 0><<<mB * 1, 256, 0, stream>>>(H2h, H2l, WT3h, WT3l, nullptr, T3, nullptr, nullptr, 128, 256, 1);
    // H3 = relu(agg(T3) + b3) -> f32 [MPAD,128]  (region B; T2 dead)
    k_agg<128, 128, true, false><<<aggBlocks, 256, 0, stream>>>(T3, H3, nullptr, nullptr, dinv, offs, deg, esrc, ew, b3, NN, MPAD);
    // P4 = agg(H3) -> split [MPAD,128]  (region A; H1 dead)
    k_agg<128, 128, false, true><<<aggBlocks, 256, 0, stream>>>(H3, nullptr, P4h, P4l, dinv, offs, deg, esrc, ew, nullptr, NN, MPAD);
    // H4 = relu(P4 @ W4 + b4) -> f32 [MPAD,200]  (region C; H2 dead)
    k_gemm<true, 0><<<mB * 2, 256, 0, stream>>>(P4h, P4l, WT4h, WT4l, b4, H4, nullptr, nullptr, 200, 128, 2);

    k_reduce<<<(NN + 255) / 256, 256, 0, stream>>>(H4, gid, gsum, NN);
    k_final<<<4, 256, 0, stream>>>(gsum, gcnt, out);
}